// Round 1
// baseline (488.811 us; speedup 1.0000x reference)
//
#include <hip/hip_runtime.h>

#define EPS 1e-5f
#define NDOM 8
#define NB 64
#define NC 256
#define NH 32
#define NW 128
#define HW (NH * NW)

// Kernel 1: per-(b,c) spatial sum/sumsq, atomically accumulated into
// per-(domain, channel) S / SQ arrays in workspace.
__global__ __launch_bounds__(256) void stats_kernel(
    const float* __restrict__ x, const int* __restrict__ dom,
    float* __restrict__ S, float* __restrict__ SQ) {
    const int bc = blockIdx.x;        // 0 .. NB*NC-1
    const int b = bc / NC;
    const int c = bc % NC;

    const float4* xp = (const float4*)(x + (size_t)bc * HW);
    float s = 0.f, sq = 0.f;
    // HW/4 = 1024 float4 per row; 256 threads -> 4 each, coalesced.
    for (int i = threadIdx.x; i < HW / 4; i += 256) {
        float4 v = xp[i];
        s  += v.x + v.y + v.z + v.w;
        sq += v.x * v.x + v.y * v.y + v.z * v.z + v.w * v.w;
    }
    // wave64 shuffle reduction
    for (int off = 32; off > 0; off >>= 1) {
        s  += __shfl_down(s, off, 64);
        sq += __shfl_down(sq, off, 64);
    }
    __shared__ float ls[4], lsq[4];
    const int lane = threadIdx.x & 63;
    const int wave = threadIdx.x >> 6;
    if (lane == 0) { ls[wave] = s; lsq[wave] = sq; }
    __syncthreads();
    if (threadIdx.x == 0) {
        float ts  = ls[0] + ls[1] + ls[2] + ls[3];
        float tsq = lsq[0] + lsq[1] + lsq[2] + lsq[3];
        const int d = dom[b] - 1;     // 1-based ids -> 0-based
        atomicAdd(&S[d * NC + c], ts);
        atomicAdd(&SQ[d * NC + c], tsq);
    }
}

// Kernel 2: normalize each (b,c) row with its domain's stats + shared affine.
__global__ __launch_bounds__(256) void norm_kernel(
    const float* __restrict__ x, const float* __restrict__ wgt,
    const float* __restrict__ bia, const int* __restrict__ dom,
    const float* __restrict__ S, const float* __restrict__ SQ,
    float* __restrict__ out) {
    const int bc = blockIdx.x;
    const int b = bc / NC;
    const int c = bc % NC;

    __shared__ float sh_scale, sh_shift;
    if (threadIdx.x == 0) {
        const int d = dom[b] - 1;
        int n = 0;
        for (int i = 0; i < NB; ++i) n += (dom[i] - 1 == d) ? 1 : 0;
        const float cnt   = fmaxf((float)n * (float)HW, 1.0f);
        const float mean  = S[d * NC + c] / cnt;
        const float var   = SQ[d * NC + c] / cnt - mean * mean;
        const float inv   = rsqrtf(var + EPS);
        const float scale = wgt[c] * inv;
        sh_scale = scale;
        sh_shift = bia[c] - mean * scale;
    }
    __syncthreads();
    const float scale = sh_scale;
    const float shift = sh_shift;

    const float4* xp = (const float4*)(x + (size_t)bc * HW);
    float4*       op = (float4*)(out + (size_t)bc * HW);
    for (int i = threadIdx.x; i < HW / 4; i += 256) {
        float4 v = xp[i];
        v.x = v.x * scale + shift;
        v.y = v.y * scale + shift;
        v.z = v.z * scale + shift;
        v.w = v.w * scale + shift;
        op[i] = v;
    }
}

extern "C" void kernel_launch(void* const* d_in, const int* in_sizes, int n_in,
                              void* d_out, int out_size, void* d_ws, size_t ws_size,
                              hipStream_t stream) {
    const float* x   = (const float*)d_in[0];
    const float* wgt = (const float*)d_in[1];
    const float* bia = (const float*)d_in[2];
    const int*   dom = (const int*)d_in[3];
    float* out = (float*)d_out;

    float* S  = (float*)d_ws;               // [NDOM, NC]
    float* SQ = S + NDOM * NC;              // [NDOM, NC]

    // d_ws is poisoned to 0xAA before every timed launch — zero the accumulators.
    hipMemsetAsync(d_ws, 0, 2 * NDOM * NC * sizeof(float), stream);

    stats_kernel<<<NB * NC, 256, 0, stream>>>(x, dom, S, SQ);
    norm_kernel<<<NB * NC, 256, 0, stream>>>(x, wgt, bia, dom, S, SQ, out);
}